// Round 11
// baseline (72.706 us; speedup 1.0000x reference)
//
#include <hip/hip_runtime.h>
#include <math.h>

// ---------------------------------------------------------------------------
// ZBL repulsion, R11: high-occupancy 3-stage pipeline.
//  - 256-thr blocks, launch_bounds(256,8): 8 waves/SIMD target (vs R10's 3)
//  - NO big LDS table (that capped occupancy at 39%); z8 is a global u8
//    gather (100 KB, L2-resident) issued ONE FULL STAGE before its compute
//    (3-stage pipeline: stream-loads t+2 | z8-gathers t+1 | compute t)
//  - za via 1 KB LDS table; nontemporal loads on read-once streams
//  - barrier-free main loop; wave scan + head atomics (sorted idx_i)
//  - native exp2/rcp/rsq lean math (validated absmax 2.4e-4)
// ---------------------------------------------------------------------------

#define LOG2E 1.4426950408889634f
#define BLK   256
#define NBLK  2048

static __device__ __forceinline__ float rcpf_(float x)  { return __builtin_amdgcn_rcpf(x); }
static __device__ __forceinline__ float rsqf_(float x)  { return __builtin_amdgcn_rsqf(x); }
static __device__ __forceinline__ float exp2f_(float x) { return __builtin_amdgcn_exp2f(x); }
static __device__ __forceinline__ float log2f_(float x) { return __builtin_amdgcn_logf(x); }

struct G { int ii, jj; float bm, dx, dy, dz; };

__global__ void zbl_k0(const float* __restrict__ an,
                       unsigned char* __restrict__ z8,
                       float* __restrict__ out, int n) {
    int i = blockIdx.x * blockDim.x + threadIdx.x;
    if (i >= n) return;
    int z = (int)(an[i] + 0.5f);
    z8[i] = (unsigned char)min(max(z, 1), 255);
    out[i] = 0.0f;                       // d_out zeroing folded in
}

static __device__ __forceinline__ G loadG(const int* __restrict__ idx_i,
                                          const int* __restrict__ idx_j,
                                          const float* __restrict__ bmk,
                                          const float* __restrict__ disp,
                                          int p, int cend) {
    G g; g.ii = -1; g.jj = 0; g.bm = 0.0f; g.dx = 0.0f; g.dy = 0.0f; g.dz = 0.0f;
    if (p < cend) {
        g.ii = __builtin_nontemporal_load(idx_i + p);
        g.jj = __builtin_nontemporal_load(idx_j + p);
        g.bm = __builtin_nontemporal_load(bmk + p);
        const float* dp = disp + (long)p * 3;
        g.dx = __builtin_nontemporal_load(dp + 0);
        g.dy = __builtin_nontemporal_load(dp + 1);
        g.dz = __builtin_nontemporal_load(dp + 2);
    }
    return g;
}

__global__ __launch_bounds__(BLK, 8) void zbl_pair_kernel(
    const float* __restrict__ disp,
    const int*   __restrict__ idx_i,       // sorted
    const int*   __restrict__ idx_j,
    const float* __restrict__ batch_mask,
    const unsigned char* __restrict__ z8g,
    const float* __restrict__ a_coef_ptr,
    const float* __restrict__ a_exp_ptr,
    const float* __restrict__ phi_c,
    const float* __restrict__ phi_e,
    float* __restrict__ out_acc,           // [N] zeroed accumulator
    int nP)
{
    __shared__ float s_za[256];
    const int tid = threadIdx.x;

    // 1 KB za table: za(z) = z^|a_exp|
    {
        float ae = fabsf(a_exp_ptr[0]);
        int z = max(tid, 1);
        s_za[tid] = exp2f_(ae * log2f_((float)z));
    }
    __syncthreads();                                  // the only barrier

    // per-thread uniforms
    const float ac_inv = rcpf_(fmaxf(fabsf(a_coef_ptr[0]), 1e-10f));
    float c0 = fabsf(phi_c[0]), c1 = fabsf(phi_c[1]);
    float c2 = fabsf(phi_c[2]), c3 = fabsf(phi_c[3]);
    const float cinv = rcpf_(fmaxf(c0 + c1 + c2 + c3, 1e-10f));
    c0 *= cinv; c1 *= cinv; c2 *= cinv; c3 *= cinv;
    const float e0 = fmaxf(fabsf(phi_e[0]), 1e-10f);
    const float e1 = fmaxf(fabsf(phi_e[1]), 1e-10f);
    const float e2 = fmaxf(fabsf(phi_e[2]), 1e-10f);
    const float e3 = fmaxf(fabsf(phi_e[3]), 1e-10f);

    // contiguous chunk per block, rounded to whole block-strides
    int chunk = (nP + NBLK - 1) / NBLK;
    chunk = (chunk + BLK - 1) & ~(BLK - 1);
    const int cbeg = blockIdx.x * chunk;
    const int cend = min(cbeg + chunk, nP);
    const int lane = tid & 63;

    // ---- prologue: stage t=0 streams + t=0 gathers; t=1 streams
    G g0 = loadG(idx_i, idx_j, batch_mask, disp, cbeg + tid,       cend);
    G g1 = loadG(idx_i, idx_j, batch_mask, disp, cbeg + BLK + tid, cend);
    int zi0 = 1, zj0 = 1;
    if (g0.ii >= 0) { zi0 = (int)z8g[g0.ii]; zj0 = (int)z8g[g0.jj]; }

    for (int pb = cbeg; pb < cend; pb += BLK) {
        // A) stream loads for stage t+2
        G g2 = loadG(idx_i, idx_j, batch_mask, disp, pb + 2 * BLK + tid, cend);

        // B) z8 gathers for stage t+1 (indices resident; full stage of slack)
        int zi1 = 1, zj1 = 1;
        if (g1.ii >= 0) { zi1 = (int)z8g[g1.ii]; zj1 = (int)z8g[g1.jj]; }

        // C) compute stage t
        float rep = 0.0f;
        int   key = -1;
        if (g0.ii >= 0) {
            const float za_i = s_za[zi0];
            const float za_j = s_za[zj0];
            const float add = 1.0f - g0.bm;
            const float dx = g0.dx + add, dy = g0.dy + add, dz = g0.dz + add;

            float d2   = fmaxf(dx * dx + dy * dy + dz * dz, 1e-20f);
            float rsq  = rsqf_(d2);
            float dist = d2 * rsq;                  // sqrt(d2); 1/dist == rsq

            float tt = dist * 0.1f;
            float tc = fminf(fmaxf(tt, 1e-9f), 1.0f - 1e-9f);
            float u  = (1.0f - 2.0f * tc) * rcpf_(tc - tc * tc);
            float s  = rcpf_(1.0f + exp2f_(u * LOG2E));
            float sw = (tt >= 1.0f) ? 1.0f : s;

            float za_sum = za_i + za_j;
            float arg  = fminf(dist * za_sum * ac_inv, 1e6f);
            float narg = -arg * LOG2E;
            float phi  = c0 * exp2f_(e0 * narg) + c1 * exp2f_(e1 * narg) +
                         c2 * exp2f_(e2 * narg) + c3 * exp2f_(e3 * narg);
            phi = fminf(fmaxf(phi, 1e-30f), 1e6f);

            float cp   = fminf((float)(zi0 * zj0), 1e4f);
            float brep = fminf(0.5f * cp * rsq, 1e6f);
            float r    = brep * phi * fmaxf(sw, 1e-30f);
            r = fminf(fmaxf(r, 0.0f), 1e6f);
            if (!(r == r)) r = 0.0f;
            rep = r * g0.bm;
            key = g0.ii;
        }

        // D) wave-level reduction on sorted keys
        {
            const int k0 = __shfl(key, 0);
            if (__all(key == k0)) {
                float v = rep;
                #pragma unroll
                for (int d = 1; d < 64; d <<= 1) v += __shfl_xor(v, d);
                if (lane == 0 && k0 >= 0) atomicAdd(&out_acc[k0], v);
            } else {
                float v = rep;
                int   k = key;
                #pragma unroll
                for (int d = 1; d < 64; d <<= 1) {
                    float nv = __shfl_down(v, d);
                    int   nk = __shfl_down(k, d);
                    if (lane + d < 64 && nk == k) v += nv;
                }
                int pk = __shfl_up(k, 1);
                bool head = (lane == 0) || (pk != k);
                if (head && k >= 0) atomicAdd(&out_acc[k], v);
            }
        }

        // E) rotate pipeline
        g0 = g1; zi0 = zi1; zj0 = zj1; g1 = g2;
    }
}

__global__ void zbl_epilogue(float* __restrict__ out,
                             const float* __restrict__ atom_mask, int n) {
    int i = blockIdx.x * blockDim.x + threadIdx.x;
    if (i >= n) return;
    float v = out[i] * atom_mask[i];
    v = fminf(fmaxf(v, 0.0f), 1e6f);
    if (!(v == v)) v = 0.0f;
    out[i] = v * 0.01f;
}

extern "C" void kernel_launch(void* const* d_in, const int* in_sizes, int n_in,
                              void* d_out, int out_size, void* d_ws, size_t ws_size,
                              hipStream_t stream) {
    const float* an         = (const float*)d_in[0];
    const float* disp       = (const float*)d_in[1];
    const int*   idx_i      = (const int*)d_in[2];
    const int*   idx_j      = (const int*)d_in[3];
    const float* atom_mask  = (const float*)d_in[4];
    const float* batch_mask = (const float*)d_in[5];
    const float* a_coef     = (const float*)d_in[8];
    const float* a_exp      = (const float*)d_in[9];
    const float* phi_c      = (const float*)d_in[10];
    const float* phi_e      = (const float*)d_in[11];

    const int nA = in_sizes[0];
    const int nP = in_sizes[2];
    float* out = (float*)d_out;

    unsigned char* z8 = (unsigned char*)d_ws;   // 100 KB, ws ample

    zbl_k0<<<(nA + 255) / 256, 256, 0, stream>>>(an, z8, out, nA);
    zbl_pair_kernel<<<NBLK, BLK, 0, stream>>>(
        disp, idx_i, idx_j, batch_mask, z8, a_coef, a_exp, phi_c, phi_e,
        out, nP);
    zbl_epilogue<<<(nA + 255) / 256, 256, 0, stream>>>(out, atom_mask, nA);
}

// Round 12
// 56.833 us; speedup vs baseline: 1.2793x; 1.2793x over previous
//
#include <hip/hip_runtime.h>
#include <math.h>

// ---------------------------------------------------------------------------
// ZBL repulsion, R12: R10 deep pipeline + high occupancy, no NT poison.
//  - 256-thr blocks, launch_bounds(256,6): ~24 waves/CU (2x R10)
//  - z8 via GLOBAL u8 gather (100 KB, L1/L2-resident), issued ONE STAGE
//    ahead of its compute; stream loads TWO stages ahead (depth-3)
//  - unroll-2: two independent 512-pair groups per iteration
//    -> 12 stream loads + 8 gathers in flight per wave
//  - 1 KB LDS za[256] table only; barrier-free main loop
//  - wave scan + head atomics (sorted idx_i); lean exp2/rcp/rsq math
// ---------------------------------------------------------------------------

#define LOG2E 1.4426950408889634f
#define BLK   256
#define NBLK  2048
#define STRD  (2 * BLK)

static __device__ __forceinline__ float rcpf_(float x)  { return __builtin_amdgcn_rcpf(x); }
static __device__ __forceinline__ float rsqf_(float x)  { return __builtin_amdgcn_rsqf(x); }
static __device__ __forceinline__ float exp2f_(float x) { return __builtin_amdgcn_exp2f(x); }
static __device__ __forceinline__ float log2f_(float x) { return __builtin_amdgcn_logf(x); }

struct f3 { float x, y, z; };
struct G  { int ii, jj; float bm, dx, dy, dz; };

__global__ void zbl_k0(const float* __restrict__ an,
                       unsigned char* __restrict__ z8,
                       float* __restrict__ out, int n) {
    int i = blockIdx.x * blockDim.x + threadIdx.x;
    if (i >= n) return;
    int z = (int)(an[i] + 0.5f);
    z8[i] = (unsigned char)min(max(z, 1), 255);
    out[i] = 0.0f;                       // d_out zeroing folded in
}

static __device__ __forceinline__ G loadG(const int* __restrict__ idx_i,
                                          const int* __restrict__ idx_j,
                                          const float* __restrict__ bmk,
                                          const float* __restrict__ disp,
                                          int p, int cend) {
    G g; g.ii = -1; g.jj = 0; g.bm = 0.0f; g.dx = 0.0f; g.dy = 0.0f; g.dz = 0.0f;
    if (p < cend) {
        g.ii = idx_i[p];
        g.jj = idx_j[p];
        g.bm = bmk[p];
        f3 d = *reinterpret_cast<const f3*>(disp + (long)p * 3);
        g.dx = d.x; g.dy = d.y; g.dz = d.z;
    }
    return g;
}

__global__ __launch_bounds__(BLK, 6) void zbl_pair_kernel(
    const float* __restrict__ disp,
    const int*   __restrict__ idx_i,       // sorted
    const int*   __restrict__ idx_j,
    const float* __restrict__ batch_mask,
    const unsigned char* __restrict__ z8g,
    const float* __restrict__ a_coef_ptr,
    const float* __restrict__ a_exp_ptr,
    const float* __restrict__ phi_c,
    const float* __restrict__ phi_e,
    float* __restrict__ out_acc,           // [N] zeroed accumulator
    int nP)
{
    __shared__ float s_za[256];
    const int tid = threadIdx.x;

    {
        float ae = fabsf(a_exp_ptr[0]);
        int z = max(tid, 1);
        s_za[tid] = exp2f_(ae * log2f_((float)z));   // za(z) = z^|a_exp|
    }
    __syncthreads();                                  // the only barrier

    // per-thread uniforms
    const float ac_inv = rcpf_(fmaxf(fabsf(a_coef_ptr[0]), 1e-10f));
    float c0 = fabsf(phi_c[0]), c1 = fabsf(phi_c[1]);
    float c2 = fabsf(phi_c[2]), c3 = fabsf(phi_c[3]);
    const float cinv = rcpf_(fmaxf(c0 + c1 + c2 + c3, 1e-10f));
    c0 *= cinv; c1 *= cinv; c2 *= cinv; c3 *= cinv;
    const float e0 = fmaxf(fabsf(phi_e[0]), 1e-10f);
    const float e1 = fmaxf(fabsf(phi_e[1]), 1e-10f);
    const float e2 = fmaxf(fabsf(phi_e[2]), 1e-10f);
    const float e3 = fmaxf(fabsf(phi_e[3]), 1e-10f);

    // contiguous chunk per block, rounded to whole unroll-strides
    int chunk = (nP + NBLK - 1) / NBLK;
    chunk = (chunk + STRD - 1) & ~(STRD - 1);
    const int cbeg = blockIdx.x * chunk;
    const int cend = min(cbeg + chunk, nP);
    const int lane = tid & 63;

#define COMPUTE_G(g, zi, zj, rep, key)                                          \
    {                                                                           \
        rep = 0.0f; key = -1;                                                   \
        if ((g).ii >= 0) {                                                      \
            const float za_i = s_za[zi];                                        \
            const float za_j = s_za[zj];                                        \
            const float add = 1.0f - (g).bm;                                    \
            const float dx = (g).dx + add, dy = (g).dy + add, dz = (g).dz + add;\
            float d2   = fmaxf(dx * dx + dy * dy + dz * dz, 1e-20f);            \
            float rsq  = rsqf_(d2);                                             \
            float dist = d2 * rsq;                                              \
            float tt = dist * 0.1f;                                             \
            float tc = fminf(fmaxf(tt, 1e-9f), 1.0f - 1e-9f);                   \
            float u  = (1.0f - 2.0f * tc) * rcpf_(tc - tc * tc);                \
            float s  = rcpf_(1.0f + exp2f_(u * LOG2E));                         \
            float sw = (tt >= 1.0f) ? 1.0f : s;                                 \
            float za_sum = za_i + za_j;                                         \
            float arg  = fminf(dist * za_sum * ac_inv, 1e6f);                   \
            float narg = -arg * LOG2E;                                          \
            float phi  = c0 * exp2f_(e0 * narg) + c1 * exp2f_(e1 * narg) +      \
                         c2 * exp2f_(e2 * narg) + c3 * exp2f_(e3 * narg);       \
            phi = fminf(fmaxf(phi, 1e-30f), 1e6f);                              \
            float cp   = fminf((float)((zi) * (zj)), 1e4f);                     \
            float brep = fminf(0.5f * cp * rsq, 1e6f);                          \
            float r    = brep * phi * fmaxf(sw, 1e-30f);                        \
            r = fminf(fmaxf(r, 0.0f), 1e6f);                                    \
            if (!(r == r)) r = 0.0f;                                            \
            rep = r * (g).bm;                                                   \
            key = (g).ii;                                                       \
        }                                                                       \
    }

#define REDUCE_G(rep, key)                                                      \
    {                                                                           \
        const int k0_ = __shfl(key, 0);                                         \
        if (__all(key == k0_)) {                                                \
            float v = rep;                                                      \
            _Pragma("unroll")                                                   \
            for (int d = 1; d < 64; d <<= 1) v += __shfl_xor(v, d);             \
            if (lane == 0 && k0_ >= 0) atomicAdd(&out_acc[k0_], v);             \
        } else {                                                                \
            float v = rep;                                                      \
            int   k = key;                                                      \
            _Pragma("unroll")                                                   \
            for (int d = 1; d < 64; d <<= 1) {                                  \
                float nv = __shfl_down(v, d);                                   \
                int   nk = __shfl_down(k, d);                                   \
                if (lane + d < 64 && nk == k) v += nv;                          \
            }                                                                   \
            int pk = __shfl_up(k, 1);                                           \
            bool head = (lane == 0) || (pk != k);                               \
            if (head && k >= 0) atomicAdd(&out_acc[k], v);                      \
        }                                                                       \
    }

    // ---- prologue: streams for stages 0,1; z gathers for stage 0
    G a0 = loadG(idx_i, idx_j, batch_mask, disp, cbeg + tid,              cend);
    G b0 = loadG(idx_i, idx_j, batch_mask, disp, cbeg + BLK + tid,        cend);
    G a1 = loadG(idx_i, idx_j, batch_mask, disp, cbeg + STRD + tid,       cend);
    G b1 = loadG(idx_i, idx_j, batch_mask, disp, cbeg + STRD + BLK + tid, cend);
    int zia0 = 1, zja0 = 1, zib0 = 1, zjb0 = 1;
    if (a0.ii >= 0) { zia0 = (int)z8g[a0.ii]; zja0 = (int)z8g[a0.jj]; }
    if (b0.ii >= 0) { zib0 = (int)z8g[b0.ii]; zjb0 = (int)z8g[b0.jj]; }

    for (int pb = cbeg; pb < cend; pb += STRD) {
        // A) stream loads for stage t+2
        G a2 = loadG(idx_i, idx_j, batch_mask, disp, pb + 2 * STRD + tid,       cend);
        G b2 = loadG(idx_i, idx_j, batch_mask, disp, pb + 2 * STRD + BLK + tid, cend);

        // B) z8 gathers for stage t+1 (one full stage of latency slack)
        int zia1 = 1, zja1 = 1, zib1 = 1, zjb1 = 1;
        if (a1.ii >= 0) { zia1 = (int)z8g[a1.ii]; zja1 = (int)z8g[a1.jj]; }
        if (b1.ii >= 0) { zib1 = (int)z8g[b1.ii]; zjb1 = (int)z8g[b1.jj]; }

        // C) compute + reduce stage t (both groups)
        float repA, repB; int keyA, keyB;
        COMPUTE_G(a0, zia0, zja0, repA, keyA);
        COMPUTE_G(b0, zib0, zjb0, repB, keyB);
        REDUCE_G(repA, keyA);
        REDUCE_G(repB, keyB);

        // D) rotate pipeline
        a0 = a1; b0 = b1; a1 = a2; b1 = b2;
        zia0 = zia1; zja0 = zja1; zib0 = zib1; zjb0 = zjb1;
    }
#undef COMPUTE_G
#undef REDUCE_G
}

__global__ void zbl_epilogue(float* __restrict__ out,
                             const float* __restrict__ atom_mask, int n) {
    int i = blockIdx.x * blockDim.x + threadIdx.x;
    if (i >= n) return;
    float v = out[i] * atom_mask[i];
    v = fminf(fmaxf(v, 0.0f), 1e6f);
    if (!(v == v)) v = 0.0f;
    out[i] = v * 0.01f;
}

extern "C" void kernel_launch(void* const* d_in, const int* in_sizes, int n_in,
                              void* d_out, int out_size, void* d_ws, size_t ws_size,
                              hipStream_t stream) {
    const float* an         = (const float*)d_in[0];
    const float* disp       = (const float*)d_in[1];
    const int*   idx_i      = (const int*)d_in[2];
    const int*   idx_j      = (const int*)d_in[3];
    const float* atom_mask  = (const float*)d_in[4];
    const float* batch_mask = (const float*)d_in[5];
    const float* a_coef     = (const float*)d_in[8];
    const float* a_exp      = (const float*)d_in[9];
    const float* phi_c      = (const float*)d_in[10];
    const float* phi_e      = (const float*)d_in[11];

    const int nA = in_sizes[0];
    const int nP = in_sizes[2];
    float* out = (float*)d_out;

    unsigned char* z8 = (unsigned char*)d_ws;   // 100 KB, ws ample

    zbl_k0<<<(nA + 255) / 256, 256, 0, stream>>>(an, z8, out, nA);
    zbl_pair_kernel<<<NBLK, BLK, 0, stream>>>(
        disp, idx_i, idx_j, batch_mask, z8, a_coef, a_exp, phi_c, phi_e,
        out, nP);
    zbl_epilogue<<<(nA + 255) / 256, 256, 0, stream>>>(out, atom_mask, nA);
}

// Round 13
// 44.576 us; speedup vs baseline: 1.6311x; 1.2750x over previous
//
#include <hip/hip_runtime.h>
#include <math.h>

// ---------------------------------------------------------------------------
// ZBL repulsion, R13: R10 skeleton + LDS-deferred reduction (no global
// atomics in the main loop -> clean counted-vmcnt stream pipeline).
//  - 1024-thr persistent blocks (256 = 1/CU), LDS z8 (100 KB) + za[256]
//  - depth-3 / unroll-2 register pipeline, barrier-free main loop
//  - wave segmented scan -> heads ds_add_f32 into per-block LDS slot
//    (slot = key - kbase, block chunk contiguous in sorted idx_i;
//    CAP=2048 slots, global-atomic fallback keeps any input correct)
//  - one __syncthreads after loop, then ~CAP-sweep flush to global
//  - native exp2/rcp/rsq lean math (validated absmax 2.4e-4)
// ---------------------------------------------------------------------------

#define LOG2E 1.4426950408889634f
#define BLK   1024
#define NBLK  256
#define STRD  (2 * BLK)
#define CAP   2048

static __device__ __forceinline__ float rcpf_(float x)  { return __builtin_amdgcn_rcpf(x); }
static __device__ __forceinline__ float rsqf_(float x)  { return __builtin_amdgcn_rsqf(x); }
static __device__ __forceinline__ float exp2f_(float x) { return __builtin_amdgcn_exp2f(x); }
static __device__ __forceinline__ float log2f_(float x) { return __builtin_amdgcn_logf(x); }

struct f3 { float x, y, z; };
struct G  { int ii, jj; float bm, dx, dy, dz; };

__global__ void zbl_k0(const float* __restrict__ an,
                       unsigned char* __restrict__ z8,
                       float* __restrict__ out, int n) {
    int i = blockIdx.x * blockDim.x + threadIdx.x;
    if (i >= n) return;
    int z = (int)(an[i] + 0.5f);
    z8[i] = (unsigned char)min(max(z, 1), 255);
    out[i] = 0.0f;                       // d_out zeroing folded in
}

static __device__ __forceinline__ G loadG(const int* __restrict__ idx_i,
                                          const int* __restrict__ idx_j,
                                          const float* __restrict__ bmk,
                                          const float* __restrict__ disp,
                                          int p, int cend) {
    G g; g.ii = -1; g.jj = 0; g.bm = 0.0f; g.dx = 0.0f; g.dy = 0.0f; g.dz = 0.0f;
    if (p < cend) {
        g.ii = idx_i[p];
        g.jj = idx_j[p];
        g.bm = bmk[p];
        f3 d = *reinterpret_cast<const f3*>(disp + (long)p * 3);
        g.dx = d.x; g.dy = d.y; g.dz = d.z;
    }
    return g;
}

__global__ __launch_bounds__(BLK) void zbl_pair_kernel(
    const float* __restrict__ disp,
    const int*   __restrict__ idx_i,       // sorted
    const int*   __restrict__ idx_j,
    const float* __restrict__ batch_mask,
    const unsigned char* __restrict__ z8g,
    const float* __restrict__ a_coef_ptr,
    const float* __restrict__ a_exp_ptr,
    const float* __restrict__ phi_c,
    const float* __restrict__ phi_e,
    float* __restrict__ out_acc,           // [N] zeroed accumulator
    int nA, int nP)
{
    extern __shared__ unsigned char smem[];
    const int nA_pad = (nA + 15) & ~15;
    unsigned char* s_z8  = smem;                                // nA_pad B
    float*         s_za  = (float*)(smem + nA_pad);             // 256 f
    float*         s_acc = (float*)(smem + nA_pad + 1024);      // CAP f

    const int tid = threadIdx.x;

    // one-time: z8 table (coalesced uint4) + za table + zero slot acc
    {
        const int nw = nA >> 4;
        const uint4* g4 = reinterpret_cast<const uint4*>(z8g);
        uint4* s4 = reinterpret_cast<uint4*>(s_z8);
        for (int i = tid; i < nw; i += BLK) s4[i] = g4[i];
        for (int i = (nw << 4) + tid; i < nA; i += BLK) s_z8[i] = z8g[i];
    }
    if (tid < 256) {
        float ae = fabsf(a_exp_ptr[0]);
        int z = max(tid, 1);
        s_za[tid] = exp2f_(ae * log2f_((float)z));   // z^|ae|
    }
    for (int i = tid; i < CAP; i += BLK) s_acc[i] = 0.0f;

    // per-thread uniforms
    const float ac_inv = rcpf_(fmaxf(fabsf(a_coef_ptr[0]), 1e-10f));
    float c0 = fabsf(phi_c[0]), c1 = fabsf(phi_c[1]);
    float c2 = fabsf(phi_c[2]), c3 = fabsf(phi_c[3]);
    const float cinv = rcpf_(fmaxf(c0 + c1 + c2 + c3, 1e-10f));
    c0 *= cinv; c1 *= cinv; c2 *= cinv; c3 *= cinv;
    const float e0 = fmaxf(fabsf(phi_e[0]), 1e-10f);
    const float e1 = fmaxf(fabsf(phi_e[1]), 1e-10f);
    const float e2 = fmaxf(fabsf(phi_e[2]), 1e-10f);
    const float e3 = fmaxf(fabsf(phi_e[3]), 1e-10f);

    int chunk = (nP + NBLK - 1) / NBLK;
    chunk = (chunk + STRD - 1) & ~(STRD - 1);
    const int cbeg = blockIdx.x * chunk;
    const int cend = min(cbeg + chunk, nP);
    const int lane = tid & 63;
    const int kbase = (cbeg < nP) ? idx_i[cbeg] : 0;

    __syncthreads();   // tables + slot acc ready

#define COMPUTE_G(g, rep, key)                                                  \
    {                                                                           \
        rep = 0.0f; key = -1;                                                   \
        if ((g).ii >= 0) {                                                      \
            const int zi = (int)s_z8[(g).ii];                                   \
            const int zj = (int)s_z8[(g).jj];                                   \
            const float za_i = s_za[zi];                                        \
            const float za_j = s_za[zj];                                        \
            const float add = 1.0f - (g).bm;                                    \
            const float dx = (g).dx + add, dy = (g).dy + add, dz = (g).dz + add;\
            float d2   = fmaxf(dx * dx + dy * dy + dz * dz, 1e-20f);            \
            float rsq  = rsqf_(d2);                                             \
            float dist = d2 * rsq;                                              \
            float tt = dist * 0.1f;                                             \
            float tc = fminf(fmaxf(tt, 1e-9f), 1.0f - 1e-9f);                   \
            float u  = (1.0f - 2.0f * tc) * rcpf_(tc - tc * tc);                \
            float s  = rcpf_(1.0f + exp2f_(u * LOG2E));                         \
            float sw = (tt >= 1.0f) ? 1.0f : s;                                 \
            float za_sum = za_i + za_j;                                         \
            float arg  = fminf(dist * za_sum * ac_inv, 1e6f);                   \
            float narg = -arg * LOG2E;                                          \
            float phi  = c0 * exp2f_(e0 * narg) + c1 * exp2f_(e1 * narg) +      \
                         c2 * exp2f_(e2 * narg) + c3 * exp2f_(e3 * narg);       \
            phi = fminf(fmaxf(phi, 1e-30f), 1e6f);                              \
            float cp   = fminf((float)(zi * zj), 1e4f);                         \
            float brep = fminf(0.5f * cp * rsq, 1e6f);                          \
            float r    = brep * phi * fmaxf(sw, 1e-30f);                        \
            r = fminf(fmaxf(r, 0.0f), 1e6f);                                    \
            if (!(r == r)) r = 0.0f;                                            \
            rep = r * (g).bm;                                                   \
            key = (g).ii;                                                       \
        }                                                                       \
    }

    // heads deposit into LDS slots (lgkm, fire-and-forget); rare fallback
#define DEPOSIT(k, v)                                                           \
    {                                                                           \
        int slot = (k) - kbase;                                                 \
        if (slot < CAP) atomicAdd(&s_acc[slot], (v));                           \
        else            atomicAdd(&out_acc[k], (v));                            \
    }

#define REDUCE_G(rep, key)                                                      \
    {                                                                           \
        const int k0_ = __shfl(key, 0);                                         \
        if (__all(key == k0_)) {                                                \
            float v = rep;                                                      \
            _Pragma("unroll")                                                   \
            for (int d = 1; d < 64; d <<= 1) v += __shfl_xor(v, d);             \
            if (lane == 0 && k0_ >= 0) DEPOSIT(k0_, v);                         \
        } else {                                                                \
            float v = rep;                                                      \
            int   k = key;                                                      \
            _Pragma("unroll")                                                   \
            for (int d = 1; d < 64; d <<= 1) {                                  \
                float nv = __shfl_down(v, d);                                   \
                int   nk = __shfl_down(k, d);                                   \
                if (lane + d < 64 && nk == k) v += nv;                          \
            }                                                                   \
            int pk = __shfl_up(k, 1);                                           \
            bool head = (lane == 0) || (pk != k);                               \
            if (head && k >= 0) DEPOSIT(k, v);                                  \
        }                                                                       \
    }

    // ---- depth-3 / unroll-2 pipeline
    G a0 = loadG(idx_i, idx_j, batch_mask, disp, cbeg + tid,              cend);
    G b0 = loadG(idx_i, idx_j, batch_mask, disp, cbeg + BLK + tid,        cend);
    G a1 = loadG(idx_i, idx_j, batch_mask, disp, cbeg + STRD + tid,       cend);
    G b1 = loadG(idx_i, idx_j, batch_mask, disp, cbeg + STRD + BLK + tid, cend);

    for (int pb = cbeg; pb < cend; pb += STRD) {
        G a2 = loadG(idx_i, idx_j, batch_mask, disp, pb + 2 * STRD + tid,       cend);
        G b2 = loadG(idx_i, idx_j, batch_mask, disp, pb + 2 * STRD + BLK + tid, cend);

        float repA, repB; int keyA, keyB;
        COMPUTE_G(a0, repA, keyA);
        COMPUTE_G(b0, repB, keyB);
        REDUCE_G(repA, keyA);
        REDUCE_G(repB, keyB);

        a0 = a1; b0 = b1; a1 = a2; b1 = b2;
    }
#undef COMPUTE_G
#undef REDUCE_G
#undef DEPOSIT

    // ---- flush LDS slots to global (few hundred nonzero per block)
    __syncthreads();
    for (int s = tid; s < CAP; s += BLK) {
        float v = s_acc[s];
        int   k = kbase + s;
        if (v != 0.0f && k < nA) atomicAdd(&out_acc[k], v);
    }
}

__global__ void zbl_epilogue(float* __restrict__ out,
                             const float* __restrict__ atom_mask, int n) {
    int i = blockIdx.x * blockDim.x + threadIdx.x;
    if (i >= n) return;
    float v = out[i] * atom_mask[i];
    v = fminf(fmaxf(v, 0.0f), 1e6f);
    if (!(v == v)) v = 0.0f;
    out[i] = v * 0.01f;
}

extern "C" void kernel_launch(void* const* d_in, const int* in_sizes, int n_in,
                              void* d_out, int out_size, void* d_ws, size_t ws_size,
                              hipStream_t stream) {
    const float* an         = (const float*)d_in[0];
    const float* disp       = (const float*)d_in[1];
    const int*   idx_i      = (const int*)d_in[2];
    const int*   idx_j      = (const int*)d_in[3];
    const float* atom_mask  = (const float*)d_in[4];
    const float* batch_mask = (const float*)d_in[5];
    const float* a_coef     = (const float*)d_in[8];
    const float* a_exp      = (const float*)d_in[9];
    const float* phi_c      = (const float*)d_in[10];
    const float* phi_e      = (const float*)d_in[11];

    const int nA = in_sizes[0];
    const int nP = in_sizes[2];
    float* out = (float*)d_out;

    unsigned char* z8 = (unsigned char*)d_ws;   // 100 KB, ws ample

    zbl_k0<<<(nA + 255) / 256, 256, 0, stream>>>(an, z8, out, nA);

    const int nA_pad = (nA + 15) & ~15;
    const size_t smem = (size_t)nA_pad + 1024 + (size_t)CAP * sizeof(float);
    zbl_pair_kernel<<<NBLK, BLK, smem, stream>>>(
        disp, idx_i, idx_j, batch_mask, z8, a_coef, a_exp, phi_c, phi_e,
        out, nA, nP);

    zbl_epilogue<<<(nA + 255) / 256, 256, 0, stream>>>(out, atom_mask, nA);
}